// Round 5
// baseline (1417.775 us; speedup 1.0000x reference)
//
#include <hip/hip_runtime.h>

#define NSEG 100000
#define DIM 32
#define NBUCKET 500          // buckets of SEG_PER_BKT consecutive segments
#define SEG_PER_BKT 200      // NBUCKET * SEG_PER_BKT == NSEG
#define NWIN 4               // row windows (x/NWIN = 128MB, fits in 256MB L3)
#define NPART (NBUCKET * NWIN)   // 2000 partitions = (bucket, window)
#define RPB 8192             // rows per partition block
#define PTHREADS 256
#define RTHREADS 1024        // gather block size
#define CHUNK 2048           // perm entries staged in LDS per step
#define SUMSTRIDE 33         // +1 pad for LDS atomic bank spread

// ---------------------------------------------------------------------------
// Q1: (bucket,window) histogram -> global totals. One LDS hist per block,
// then one global atomicAdd per nonempty partition.
// ---------------------------------------------------------------------------
__global__ void q1_hist(const int* __restrict__ idx, int* __restrict__ gtot,
                        int n_rows, int wrows) {
    __shared__ int hist[NPART];
    int t = threadIdx.x, blk = blockIdx.x;
    for (int i = t; i < NPART; i += PTHREADS) hist[i] = 0;
    __syncthreads();
    int base = blk * RPB;
    for (int it = 0; it < RPB / PTHREADS; ++it) {
        int row = base + it * PTHREADS + t;
        if (row < n_rows) {
            int seg = idx[row];
            int p = (seg / SEG_PER_BKT) * NWIN + row / wrows;
            atomicAdd(&hist[p], 1);
        }
    }
    __syncthreads();
    for (int i = t; i < NPART; i += PTHREADS)
        if (hist[i]) atomicAdd(&gtot[i], hist[i]);
}

// ---------------------------------------------------------------------------
// Q2: exclusive scan of 2000 partition totals -> part_base[2001] + cursors.
// ---------------------------------------------------------------------------
__global__ void q2_scan(const int* __restrict__ gtot,
                        int* __restrict__ part_base,
                        int* __restrict__ gcursor) {
    int lane = threadIdx.x;                 // 64 threads = 1 wave
    const int cpl = (NPART + 63) / 64;      // 32
    int s0 = lane * cpl, s1 = min(NPART, s0 + cpl);
    int csum = 0;
    for (int i = s0; i < s1; ++i) csum += gtot[i];
    int v = csum;
    for (int d = 1; d < 64; d <<= 1) {
        int u = __shfl_up(v, d, 64);
        if (lane >= d) v += u;
    }
    int run = v - csum;
    for (int i = s0; i < s1; ++i) {
        part_base[i] = run;
        gcursor[i] = run;
        run += gtot[i];
    }
    if (lane == 63) part_base[NPART] = v;
}

// ---------------------------------------------------------------------------
// Q3: block-local counting sort (LDS) by partition key, reserve global runs
// via one cursor atomicAdd per nonempty partition, then fully COALESCED perm
// write-out. perm packs (local_seg:8 | row:24).
// ---------------------------------------------------------------------------
__global__ void __launch_bounds__(PTHREADS)
q3_partition(const int* __restrict__ idx, int* __restrict__ gcursor,
             unsigned int* __restrict__ perm, int n_rows, int wrows) {
    __shared__ int idxb[RPB];              // 32KB
    __shared__ unsigned int buf[RPB];      // 32KB
    __shared__ int hist[NPART];            // 8KB
    __shared__ int scanb[NPART];           // 8KB
    __shared__ int runb[NPART];            // 8KB -> 88KB total
    int t = threadIdx.x, blk = blockIdx.x;
    int base = blk * RPB;
    int rows_blk = min(RPB, n_rows - base);

    for (int i = t; i < NPART; i += PTHREADS) hist[i] = 0;
    for (int i = t; i < rows_blk; i += PTHREADS) idxb[i] = idx[base + i];
    __syncthreads();

    for (int i = t; i < rows_blk; i += PTHREADS) {
        int p = (idxb[i] / SEG_PER_BKT) * NWIN + (base + i) / wrows;
        atomicAdd(&hist[p], 1);
    }
    __syncthreads();

    // wave-0 exclusive scan of hist -> scanb (hist preserved)
    if (t < 64) {
        const int cpl = (NPART + 63) / 64;  // 32
        int s0 = t * cpl, s1 = min(NPART, s0 + cpl);
        int csum = 0;
        for (int i = s0; i < s1; ++i) csum += hist[i];
        int v = csum;
        for (int d = 1; d < 64; d <<= 1) {
            int u = __shfl_up(v, d, 64);
            if (t >= d) v += u;
        }
        int run = v - csum;
        for (int i = s0; i < s1; ++i) {
            scanb[i] = run;
            run += hist[i];
        }
    }
    __syncthreads();

    // reserve contiguous global slots per nonempty partition
    for (int i = t; i < NPART; i += PTHREADS) {
        int c = hist[i];
        if (c > 0) runb[i] = atomicAdd(&gcursor[i], c);
    }
    __syncthreads();

    // rank-scatter into partition-ordered LDS (atomicSub rank; destroys hist)
    for (int i = t; i < rows_blk; i += PTHREADS) {
        int seg = idxb[i];
        int p = (seg / SEG_PER_BKT) * NWIN + (base + i) / wrows;
        int r = atomicSub(&hist[p], 1) - 1;
        buf[scanb[p] + r] = ((unsigned int)seg << 13) | (unsigned int)i;
    }
    __syncthreads();

    // coalesced write-out: consecutive slots -> consecutive global positions
    for (int s = t; s < rows_blk; s += PTHREADS) {
        unsigned int e = buf[s];
        int seg = (int)(e >> 13);
        int lr  = (int)(e & 8191u);
        int row = base + lr;
        int b   = seg / SEG_PER_BKT;
        int p   = b * NWIN + row / wrows;
        int gpos = runb[p] + (s - scanb[p]);
        perm[gpos] = ((unsigned int)(seg - b * SEG_PER_BKT) << 24) |
                     (unsigned int)row;
    }
}

// ---------------------------------------------------------------------------
// TOUCH: stream one 128MB row-window of x sequentially -> populates L3 so the
// following gather hits cache instead of activate-bound random HBM.
// ---------------------------------------------------------------------------
__global__ void touch_window(const float4* __restrict__ x4,
                             long long f4_begin, long long f4_end) {
    long long stride = (long long)gridDim.x * blockDim.x;
    long long i = (long long)blockIdx.x * blockDim.x + threadIdx.x + f4_begin;
    float acc = 0.0f;
    for (; i < f4_end; i += stride) {
        float4 v = x4[i];
        acc += v.x + v.y + v.z + v.w;
    }
    asm volatile("" :: "v"(acc));   // keep loads alive (rule #17)
}

// ---------------------------------------------------------------------------
// G5: one block per bucket, gathers only rows of window w (contiguous perm
// range, L3-resident after touch). LDS float atomic accumulate (stride-33),
// partials pass through out/gcnt between windows; final window divides.
// ---------------------------------------------------------------------------
__global__ void __launch_bounds__(RTHREADS)
g5_gather(const float* __restrict__ x, const unsigned int* __restrict__ perm,
          const int* __restrict__ part_base, float* __restrict__ out,
          int* __restrict__ gcnt, int w) {
    __shared__ float sums[SEG_PER_BKT * SUMSTRIDE];   // 26.4KB
    __shared__ int cntl[SEG_PER_BKT];
    __shared__ unsigned int pbuf[CHUNK];              // 8KB
    int t = threadIdx.x, b = blockIdx.x;

    if (w == 0) {
        for (int i = t; i < SEG_PER_BKT * SUMSTRIDE; i += RTHREADS) sums[i] = 0.0f;
        for (int i = t; i < SEG_PER_BKT; i += RTHREADS) cntl[i] = 0;
    } else {
        for (int e = t; e < SEG_PER_BKT * DIM; e += RTHREADS)
            sums[(e >> 5) * SUMSTRIDE + (e & 31)] =
                out[(size_t)b * SEG_PER_BKT * DIM + e];
        for (int i = t; i < SEG_PER_BKT; i += RTHREADS)
            cntl[i] = gcnt[b * SEG_PER_BKT + i];
    }
    int start = part_base[b * NWIN + w];
    int end   = part_base[b * NWIN + w + 1];
    __syncthreads();

    const float4* x4 = (const float4*)x;
    int g = t >> 3, sub = t & 7;   // 128 groups of 8 lanes; 1 float4/lane/row

    for (int cb = start; cb < end; cb += CHUNK) {
        int m = min(CHUNK, end - cb);
        for (int i = t; i < m; i += RTHREADS) pbuf[i] = perm[cb + i];
        __syncthreads();
        int i = g;
        for (; i + 384 < m; i += 512) {
            unsigned int e0 = pbuf[i];
            unsigned int e1 = pbuf[i + 128];
            unsigned int e2 = pbuf[i + 256];
            unsigned int e3 = pbuf[i + 384];
            float4 v0 = x4[(size_t)(e0 & 0xFFFFFFu) * 8 + sub];
            float4 v1 = x4[(size_t)(e1 & 0xFFFFFFu) * 8 + sub];
            float4 v2 = x4[(size_t)(e2 & 0xFFFFFFu) * 8 + sub];
            float4 v3 = x4[(size_t)(e3 & 0xFFFFFFu) * 8 + sub];
            int s0 = (int)(e0 >> 24) * SUMSTRIDE + sub * 4;
            int s1 = (int)(e1 >> 24) * SUMSTRIDE + sub * 4;
            int s2 = (int)(e2 >> 24) * SUMSTRIDE + sub * 4;
            int s3 = (int)(e3 >> 24) * SUMSTRIDE + sub * 4;
            atomicAdd(&sums[s0 + 0], v0.x); atomicAdd(&sums[s0 + 1], v0.y);
            atomicAdd(&sums[s0 + 2], v0.z); atomicAdd(&sums[s0 + 3], v0.w);
            atomicAdd(&sums[s1 + 0], v1.x); atomicAdd(&sums[s1 + 1], v1.y);
            atomicAdd(&sums[s1 + 2], v1.z); atomicAdd(&sums[s1 + 3], v1.w);
            atomicAdd(&sums[s2 + 0], v2.x); atomicAdd(&sums[s2 + 1], v2.y);
            atomicAdd(&sums[s2 + 2], v2.z); atomicAdd(&sums[s2 + 3], v2.w);
            atomicAdd(&sums[s3 + 0], v3.x); atomicAdd(&sums[s3 + 1], v3.y);
            atomicAdd(&sums[s3 + 2], v3.z); atomicAdd(&sums[s3 + 3], v3.w);
            if (sub == 0) {
                atomicAdd(&cntl[e0 >> 24], 1);
                atomicAdd(&cntl[e1 >> 24], 1);
                atomicAdd(&cntl[e2 >> 24], 1);
                atomicAdd(&cntl[e3 >> 24], 1);
            }
        }
        for (; i < m; i += 128) {
            unsigned int e = pbuf[i];
            float4 v = x4[(size_t)(e & 0xFFFFFFu) * 8 + sub];
            int s0 = (int)(e >> 24) * SUMSTRIDE + sub * 4;
            atomicAdd(&sums[s0 + 0], v.x); atomicAdd(&sums[s0 + 1], v.y);
            atomicAdd(&sums[s0 + 2], v.z); atomicAdd(&sums[s0 + 3], v.w);
            if (sub == 0) atomicAdd(&cntl[e >> 24], 1);
        }
        __syncthreads();
    }

    if (w == NWIN - 1) {   // final: fused divide + store
        for (int e = t; e < SEG_PER_BKT * DIM; e += RTHREADS) {
            int ls = e >> 5, col = e & 31;
            float cf = (float)cntl[ls];
            out[(size_t)b * SEG_PER_BKT * DIM + e] =
                sums[ls * SUMSTRIDE + col] / fmaxf(cf, 1.0f);
        }
    } else {               // spill partials
        for (int e = t; e < SEG_PER_BKT * DIM; e += RTHREADS)
            out[(size_t)b * SEG_PER_BKT * DIM + e] =
                sums[(e >> 5) * SUMSTRIDE + (e & 31)];
        for (int i = t; i < SEG_PER_BKT; i += RTHREADS)
            gcnt[b * SEG_PER_BKT + i] = cntl[i];
    }
}

// ---------------------------------------------------------------------------
// Fallback path (harness-verified in round 0): element-wise float atomics.
// ---------------------------------------------------------------------------
__global__ void scatter_sum_kernel(const float* __restrict__ x,
                                   const int* __restrict__ idx,
                                   float* __restrict__ sums,
                                   float* __restrict__ cnts,
                                   int n_elems) {
    int i = blockIdx.x * blockDim.x + threadIdx.x;
    if (i >= n_elems) return;
    int row = i >> 5;
    int col = i & 31;
    int seg = idx[row];
    atomicAdd(&sums[seg * DIM + col], x[i]);
    if (col == 0) atomicAdd(&cnts[seg], 1.0f);
}

__global__ void divide_kernel(float* __restrict__ out,
                              const float* __restrict__ cnts, int n) {
    int i = blockIdx.x * blockDim.x + threadIdx.x;
    if (i >= n) return;
    float c = cnts[i >> 5];
    out[i] = out[i] / fmaxf(c, 1.0f);
}

// ---------------------------------------------------------------------------

extern "C" void kernel_launch(void* const* d_in, const int* in_sizes, int n_in,
                              void* d_out, int out_size, void* d_ws, size_t ws_size,
                              hipStream_t stream) {
    const float* x   = (const float*)d_in[0];
    const int*   idx = (const int*)d_in[1];
    float* out = (float*)d_out;

    int n_elems = in_sizes[0];        // 4,000,000 * 32
    int n_rows  = n_elems / DIM;      // 4,000,000
    int nblk    = (n_rows + RPB - 1) / RPB;       // 489
    int wrows   = (n_rows + NWIN - 1) / NWIN;     // 1,000,000 rows = 128MB

    // ws (ints): perm[n_rows] | gtot[NPART] | part_base[NPART+1]
    //          | gcursor[NPART] | gcnt[NSEG]
    size_t need = ((size_t)n_rows + NPART + (NPART + 1) + NPART + NSEG)
                  * sizeof(int);

    if (ws_size >= need && n_rows <= (1 << 24)) {
        unsigned int* perm = (unsigned int*)d_ws;
        int* gtot      = (int*)(perm + n_rows);
        int* part_base = gtot + NPART;
        int* gcursor   = part_base + NPART + 1;
        int* gcnt      = gcursor + NPART;

        hipMemsetAsync(gtot, 0, NPART * sizeof(int), stream);
        q1_hist<<<nblk, PTHREADS, 0, stream>>>(idx, gtot, n_rows, wrows);
        q2_scan<<<1, 64, 0, stream>>>(gtot, part_base, gcursor);
        q3_partition<<<nblk, PTHREADS, 0, stream>>>(idx, gcursor, perm,
                                                    n_rows, wrows);
        const float4* x4 = (const float4*)x;
        for (int w = 0; w < NWIN; ++w) {
            long long rb = (long long)w * wrows;
            long long re = rb + wrows;
            if (re > n_rows) re = n_rows;
            if (rb < re)
                touch_window<<<2048, 256, 0, stream>>>(x4, rb * 8, re * 8);
            g5_gather<<<NBUCKET, RTHREADS, 0, stream>>>(x, perm, part_base,
                                                        out, gcnt, w);
        }
    } else {
        float* cnts = (float*)d_ws;
        hipMemsetAsync(d_out, 0, (size_t)out_size * sizeof(float), stream);
        hipMemsetAsync(d_ws, 0, (size_t)NSEG * sizeof(float), stream);

        const int threads = 256;
        int blocks = (n_elems + threads - 1) / threads;
        scatter_sum_kernel<<<blocks, threads, 0, stream>>>(x, idx, out, cnts, n_elems);
        int blocks2 = (out_size + threads - 1) / threads;
        divide_kernel<<<blocks2, threads, 0, stream>>>(out, cnts, out_size);
    }
}